// Round 1
// baseline (1302.732 us; speedup 1.0000x reference)
//
#include <hip/hip_runtime.h>
#include <hip/hip_bf16.h>

#define NTOK 8192
#define DDIM 768
#define HDIM 3072
#define NEXP 8
#define MROWS (NTOK*2)

typedef float f32x4 __attribute__((ext_vector_type(4)));
typedef short bf16x8 __attribute__((ext_vector_type(8)));
typedef unsigned short u16x4 __attribute__((ext_vector_type(4)));

__device__ __forceinline__ unsigned short f2bf(float f) {
  union { float f; unsigned u; } v; v.f = f;
  unsigned r = v.u + 0x7fffu + ((v.u >> 16) & 1u);  // RN-even
  return (unsigned short)(r >> 16);
}

// ---------------- gating: logits, softmax sums, top-2, scatter ----------------
__global__ __launch_bounds__(128) void gating_kernel(
    const float* __restrict__ x, const float* __restrict__ gw,
    const float* __restrict__ nw, const float* __restrict__ noise,
    int* counts, float* sums, int* tok_list, float* gate_list,
    int* tok_top, float* gate_top)
{
  __shared__ float s_gw[NEXP*DDIM];
  __shared__ float s_sums[NEXP];
  __shared__ float s_nw[NEXP];
  int tid = threadIdx.x;
  for (int i = tid; i < NEXP*DDIM/4; i += 128)
    ((f32x4*)s_gw)[i] = ((const f32x4*)gw)[i];
  if (tid < NEXP) { s_sums[tid] = 0.f; s_nw[tid] = nw[tid]; }
  __syncthreads();
  int t = blockIdx.x*128 + tid;
  float acc[NEXP];
  #pragma unroll
  for (int e = 0; e < NEXP; ++e) acc[e] = 0.f;
  const f32x4* xr = (const f32x4*)(x + (size_t)t*DDIM);
  for (int d4 = 0; d4 < DDIM/4; ++d4) {
    f32x4 xv = xr[d4];
    #pragma unroll
    for (int e = 0; e < NEXP; ++e) {
      f32x4 g = *(const f32x4*)&s_gw[e*DDIM + d4*4];
      acc[e] += xv.x*g.x + xv.y*g.y + xv.z*g.z + xv.w*g.w;
    }
  }
  // clean softmax for the load-balance mean
  float m = acc[0];
  #pragma unroll
  for (int e = 1; e < NEXP; ++e) m = fmaxf(m, acc[e]);
  float p[NEXP], s = 0.f;
  #pragma unroll
  for (int e = 0; e < NEXP; ++e) { p[e] = __expf(acc[e]-m); s += p[e]; }
  float inv = 1.f/s;
  #pragma unroll
  for (int e = 0; e < NEXP; ++e) atomicAdd(&s_sums[e], p[e]*inv);
  // noisy logits (noise_weight is zeros at init but handle generically)
  float ln[NEXP];
  #pragma unroll
  for (int e = 0; e < NEXP; ++e) ln[e] = acc[e] + noise[(size_t)t*NEXP+e]*s_nw[e];
  // top-2 (strict > matches jax stable descending tie-break)
  int i0 = 0; float v0 = ln[0];
  #pragma unroll
  for (int e = 1; e < NEXP; ++e) if (ln[e] > v0) { v0 = ln[e]; i0 = e; }
  int i1 = -1; float v1 = 0.f;
  #pragma unroll
  for (int e = 0; e < NEXP; ++e)
    if (e != i0 && (i1 < 0 || ln[e] > v1)) { v1 = ln[e]; i1 = e; }
  float e1 = __expf(v1 - v0);
  float g0 = 1.f/(1.f + e1);
  float g1 = e1*g0;
  int p0 = atomicAdd(&counts[i0], 1);
  tok_list[i0*NTOK + p0] = t; gate_list[i0*NTOK + p0] = g0;
  int p1 = atomicAdd(&counts[i1], 1);
  tok_list[i1*NTOK + p1] = t; gate_list[i1*NTOK + p1] = g1;
  tok_top[2*t] = i0; tok_top[2*t+1] = i1;
  gate_top[2*t] = g0; gate_top[2*t+1] = g1;
  __syncthreads();
  if (tid < NEXP) atomicAdd(&sums[tid], s_sums[tid]);
}

// ---------------- offsets prefix + load-balance loss ----------------
__global__ void finalize_kernel(const int* counts, const float* sums,
                                int* offsets, float* loss_out)
{
  if (threadIdx.x == 0) {
    int o = 0;
    #pragma unroll
    for (int e = 0; e < NEXP; ++e) { offsets[e] = o; o += counts[e]; }
    offsets[NEXP] = o;
    float l = 0.f;
    #pragma unroll
    for (int e = 0; e < NEXP; ++e) {
      float dv = sums[e]*(1.f/(float)NTOK) - 1.f/(float)NEXP;
      l += dv*dv;
    }
    loss_out[0] = l*(0.01f/(float)NEXP);
  }
}

// ---------------- x -> bf16 ----------------
__global__ __launch_bounds__(256) void cvt_x_kernel(const float* __restrict__ x,
                                                    unsigned short* __restrict__ xb)
{
  int i = blockIdx.x*256 + threadIdx.x;
  f32x4 v = ((const f32x4*)x)[i];
  u16x4 o; o.x = f2bf(v.x); o.y = f2bf(v.y); o.z = f2bf(v.z); o.w = f2bf(v.w);
  ((u16x4*)xb)[i] = o;
}

// ---------------- compact per-expert lists into M=16384 rows ----------------
__global__ __launch_bounds__(256) void compact_kernel(
    const int* __restrict__ counts, const int* __restrict__ offsets,
    const int* __restrict__ tok_list, const float* __restrict__ gate_list,
    int* __restrict__ row_token, float* __restrict__ row_gate)
{
  int e = blockIdx.y;
  int pos = blockIdx.x*256 + threadIdx.x;
  if (pos < counts[e]) {
    int r = offsets[e] + pos;
    row_token[r] = tok_list[e*NTOK + pos];
    row_gate[r]  = gate_list[e*NTOK + pos];
  }
}

// ---------------- y init with gated biases (covers all outputs) ----------------
__global__ __launch_bounds__(256) void init_y_kernel(
    const int* __restrict__ tok_top, const float* __restrict__ gate_top,
    const float* __restrict__ bp, float* __restrict__ y)
{
  int i = blockIdx.x*256 + threadIdx.x;       // float4 index over y
  int t = i / (DDIM/4);
  int d4 = i % (DDIM/4);
  int e0 = tok_top[2*t], e1 = tok_top[2*t+1];
  float g0 = gate_top[2*t], g1 = gate_top[2*t+1];
  f32x4 b0 = ((const f32x4*)(bp + (size_t)e0*DDIM))[d4];
  f32x4 b1v = ((const f32x4*)(bp + (size_t)e1*DDIM))[d4];
  ((f32x4*)y)[i] = g0*b0 + g1*b1v;
}

// ---------------- FFN1: h = (x@w1+b1)*silu(x@w2+b2), bf16 MFMA ----------------
// block: 256 thr = 4 waves; tile 128 rows x 64 h-cols; wave wc owns 16 paired cols.
// A (gathered x rows) staged in LDS (stride 40 shorts -> 2-way-free banks);
// B fragments loaded directly from global fp32 (coalesced: 16 lanes x 4B, 4 rows)
// and converted in-register -> no LDS transpose conflicts.
__global__ __launch_bounds__(256) void ffn1_kernel(
    const unsigned short* __restrict__ xb,
    const float* __restrict__ w1, const float* __restrict__ b1,
    const float* __restrict__ w2, const float* __restrict__ b2,
    const int* __restrict__ offsets, const int* __restrict__ row_token,
    unsigned short* __restrict__ h_buf, int h_base, int HC)
{
  int e = blockIdx.z;
  int r_lo = offsets[e];
  int rows_e = offsets[e+1] - r_lo;
  int bx = blockIdx.x;
  if (bx*128 >= rows_e) return;
  int r0 = r_lo + bx*128;
  int rows_valid = rows_e - bx*128; if (rows_valid > 128) rows_valid = 128;
  int h0 = h_base + blockIdx.y*64;

  __shared__ unsigned short sA[128*40];
  __shared__ int s_tok[128];

  int tid = threadIdx.x;
  if (tid < 128) {
    int r = r0 + tid; if (r > MROWS-1) r = MROWS-1;
    s_tok[tid] = row_token[r];
  }
  int lane = tid & 63;
  int wc = tid >> 6;
  int quad = lane >> 4, l16 = lane & 15;

  const float* w1p = w1 + (size_t)e*DDIM*HDIM + h0 + wc*16 + l16;
  const float* w2p = w2 + (size_t)e*DDIM*HDIM + h0 + wc*16 + l16;

  f32x4 acc1[8], acc2[8];
  #pragma unroll
  for (int i = 0; i < 8; ++i) { acc1[i] = (f32x4){0,0,0,0}; acc2[i] = (f32x4){0,0,0,0}; }
  __syncthreads();

  for (int k0 = 0; k0 < DDIM; k0 += 32) {
    #pragma unroll
    for (int i = 0; i < 2; ++i) {            // stage A: 128x32 bf16
      int c = i*256 + tid;
      int row = c >> 2, k8 = c & 3;
      bf16x8 v = *(const bf16x8*)(xb + (size_t)s_tok[row]*DDIM + k0 + k8*8);
      *(bf16x8*)&sA[row*40 + k8*8] = v;
    }
    float b1v[8], b2v[8];
    #pragma unroll
    for (int j = 0; j < 8; ++j) {            // B frags direct from global
      size_t ro = (size_t)(k0 + quad*8 + j) * HDIM;
      b1v[j] = w1p[ro];
      b2v[j] = w2p[ro];
    }
    bf16x8 bf1, bf2;
    #pragma unroll
    for (int j = 0; j < 8; ++j) { bf1[j] = (short)f2bf(b1v[j]); bf2[j] = (short)f2bf(b2v[j]); }
    __syncthreads();
    #pragma unroll
    for (int mt = 0; mt < 8; ++mt) {
      bf16x8 af = *(const bf16x8*)&sA[(mt*16 + l16)*40 + quad*8];
      acc1[mt] = __builtin_amdgcn_mfma_f32_16x16x32_bf16(af, bf1, acc1[mt], 0, 0, 0);
      acc2[mt] = __builtin_amdgcn_mfma_f32_16x16x32_bf16(af, bf2, acc2[mt], 0, 0, 0);
    }
    __syncthreads();
  }
  // SwiGLU epilogue; C/D layout: col=lane&15, row=quad*4+reg (m89-verified)
  int hcol = h0 + wc*16 + l16;
  float bb1 = b1[(size_t)e*HDIM + hcol];
  float bb2 = b2[(size_t)e*HDIM + hcol];
  int hl = hcol - h_base;
  #pragma unroll
  for (int mt = 0; mt < 8; ++mt) {
    #pragma unroll
    for (int r = 0; r < 4; ++r) {
      int row = mt*16 + quad*4 + r;
      if (row < rows_valid) {
        float c1 = acc1[mt][r] + bb1;
        float c2 = acc2[mt][r] + bb2;
        float hv = c1 * (c2 / (1.f + __expf(-c2)));
        h_buf[(size_t)(r0 + row)*HC + hl] = f2bf(hv);
      }
    }
  }
}

// ---------------- FFN2: y += gate * (h @ wp), atomic combine ----------------
__global__ __launch_bounds__(256) void ffn2_kernel(
    const unsigned short* __restrict__ h_buf, const float* __restrict__ wp,
    const int* __restrict__ offsets, const int* __restrict__ row_token,
    const float* __restrict__ row_gate, float* __restrict__ y, int h_base, int HC)
{
  int e = blockIdx.z;
  int r_lo = offsets[e];
  int rows_e = offsets[e+1] - r_lo;
  int bx = blockIdx.x;
  if (bx*128 >= rows_e) return;
  int r0 = r_lo + bx*128;
  int rows_valid = rows_e - bx*128; if (rows_valid > 128) rows_valid = 128;
  int c0 = blockIdx.y*128;

  __shared__ unsigned short sA[128*40];
  __shared__ int s_tok[128];
  __shared__ float s_gate[128];

  int tid = threadIdx.x;
  if (tid < 128) {
    int r = r0 + tid; if (r > MROWS-1) r = MROWS-1;
    s_tok[tid]  = row_token[r];
    s_gate[tid] = row_gate[r];
  }
  int lane = tid & 63;
  int wc = tid >> 6;
  int quad = lane >> 4, l16 = lane & 15;

  const float* wp0 = wp + (size_t)e*HDIM*DDIM + c0 + wc*32 + l16;

  f32x4 acc[8][2];
  #pragma unroll
  for (int i = 0; i < 8; ++i) { acc[i][0] = (f32x4){0,0,0,0}; acc[i][1] = (f32x4){0,0,0,0}; }
  __syncthreads();

  for (int k0 = 0; k0 < HC; k0 += 32) {
    #pragma unroll
    for (int i = 0; i < 2; ++i) {            // stage A: 128x32 h bf16 (compact rows)
      int c = i*256 + tid;
      int row = c >> 2, k8 = c & 3;
      int rr = r0 + row; if (rr > MROWS-1) rr = MROWS-1;
      bf16x8 v = *(const bf16x8*)(h_buf + (size_t)rr*HC + k0 + k8*8);
      *(bf16x8*)&sA[row*40 + k8*8] = v;
    }
    float bv[2][8];
    #pragma unroll
    for (int nt = 0; nt < 2; ++nt)
      #pragma unroll
      for (int j = 0; j < 8; ++j)
        bv[nt][j] = wp0[(size_t)(h_base + k0 + quad*8 + j)*DDIM + nt*16];
    bf16x8 bfr[2];
    #pragma unroll
    for (int nt = 0; nt < 2; ++nt)
      #pragma unroll
      for (int j = 0; j < 8; ++j) bfr[nt][j] = (short)f2bf(bv[nt][j]);
    __syncthreads();
    #pragma unroll
    for (int mt = 0; mt < 8; ++mt) {
      bf16x8 af = *(const bf16x8*)&sA[(mt*16 + l16)*40 + quad*8];
      acc[mt][0] = __builtin_amdgcn_mfma_f32_16x16x32_bf16(af, bfr[0], acc[mt][0], 0, 0, 0);
      acc[mt][1] = __builtin_amdgcn_mfma_f32_16x16x32_bf16(af, bfr[1], acc[mt][1], 0, 0, 0);
    }
    __syncthreads();
  }
  #pragma unroll
  for (int nt = 0; nt < 2; ++nt) {
    int col = c0 + wc*32 + nt*16 + l16;
    #pragma unroll
    for (int mt = 0; mt < 8; ++mt) {
      #pragma unroll
      for (int r = 0; r < 4; ++r) {
        int row = mt*16 + quad*4 + r;
        if (row < rows_valid)
          atomicAdd(&y[(size_t)s_tok[row]*DDIM + col], s_gate[row]*acc[mt][nt][r]);
      }
    }
  }
}

extern "C" void kernel_launch(void* const* d_in, const int* in_sizes, int n_in,
                              void* d_out, int out_size, void* d_ws, size_t ws_size,
                              hipStream_t stream)
{
  (void)in_sizes; (void)n_in; (void)out_size;
  const float* x     = (const float*)d_in[0];
  const float* gw    = (const float*)d_in[1];
  const float* nw    = (const float*)d_in[2];
  const float* noise = (const float*)d_in[3];
  const float* w1    = (const float*)d_in[4];
  const float* b1    = (const float*)d_in[5];
  const float* w2    = (const float*)d_in[6];
  const float* b2    = (const float*)d_in[7];
  const float* wp    = (const float*)d_in[8];
  const float* bp    = (const float*)d_in[9];
  float* y = (float*)d_out;

  char* ws = (char*)d_ws;
  int*   counts   = (int*)(ws + 0);     // 8 ints   (zeroed each launch)
  float* sums     = (float*)(ws + 64);  // 8 floats (zeroed each launch)
  int*   offsets  = (int*)(ws + 128);   // 9 ints
  size_t off = 256;
  int*   tok_list  = (int*)(ws + off);   off += (size_t)NEXP*NTOK*4;
  float* gate_list = (float*)(ws + off); off += (size_t)NEXP*NTOK*4;
  int*   tok_top   = (int*)(ws + off);   off += (size_t)NTOK*2*4;
  float* gate_top  = (float*)(ws + off); off += (size_t)NTOK*2*4;
  int*   row_token = (int*)(ws + off);   off += (size_t)MROWS*4;
  float* row_gate  = (float*)(ws + off); off += (size_t)MROWS*4;
  unsigned short* xb = (unsigned short*)(ws + off); off += (size_t)NTOK*DDIM*2;

  // h chunk width: largest that fits ws (h_buf is MROWS x HC bf16)
  static const int hc_opts[6] = {3072, 1536, 768, 384, 192, 64};
  int HC = 64;
  for (int i = 0; i < 6; ++i)
    if (off + (size_t)MROWS*hc_opts[i]*2 <= ws_size) { HC = hc_opts[i]; break; }
  unsigned short* h_buf = (unsigned short*)(ws + off);

  hipMemsetAsync(d_ws, 0, 256, stream);
  gating_kernel<<<NTOK/128, 128, 0, stream>>>(x, gw, nw, noise, counts, sums,
                                              tok_list, gate_list, tok_top, gate_top);
  finalize_kernel<<<1, 64, 0, stream>>>(counts, sums, offsets, y + (size_t)NTOK*DDIM);
  cvt_x_kernel<<<NTOK*DDIM/1024, 256, 0, stream>>>(x, xb);
  compact_kernel<<<dim3(NTOK/256, NEXP), 256, 0, stream>>>(counts, offsets, tok_list,
                                                           gate_list, row_token, row_gate);
  init_y_kernel<<<NTOK*DDIM/1024, 256, 0, stream>>>(tok_top, gate_top, bp, y);
  int nch = HDIM / HC;
  for (int c = 0; c < nch; ++c) {
    ffn1_kernel<<<dim3(64, HC/64, NEXP), 256, 0, stream>>>(xb, w1, b1, w2, b2, offsets,
                                                           row_token, h_buf, c*HC, HC);
    ffn2_kernel<<<dim3(64, DDIM/128, NEXP), 256, 0, stream>>>(h_buf, wp, offsets, row_token,
                                                              row_gate, y, c*HC, HC);
  }
}

// Round 2
// 999.284 us; speedup vs baseline: 1.3037x; 1.3037x over previous
//
#include <hip/hip_runtime.h>
#include <hip/hip_bf16.h>

#define NTOK 8192
#define DDIM 768
#define HDIM 3072
#define NEXP 8
#define MROWS (NTOK*2)

typedef float f32x4 __attribute__((ext_vector_type(4)));
typedef short bf16x8 __attribute__((ext_vector_type(8)));
typedef unsigned short u16x4 __attribute__((ext_vector_type(4)));

__device__ __forceinline__ unsigned short f2bf(float f) {
  union { float f; unsigned u; } v; v.f = f;
  unsigned r = v.u + 0x7fffu + ((v.u >> 16) & 1u);  // RN-even
  return (unsigned short)(r >> 16);
}

// async global->LDS, 16B per lane; LDS dest = wave-uniform base + lane*16
typedef __attribute__((address_space(3))) unsigned int* lds_ptr_t;
typedef const __attribute__((address_space(1))) unsigned int* gbl_ptr_t;
__device__ __forceinline__ void async16(const void* g, void* l) {
  __builtin_amdgcn_global_load_lds((gbl_ptr_t)g, (lds_ptr_t)l, 16, 0, 0);
}

// ---------------- gating: logits, softmax sums, top-2, scatter ----------------
__global__ __launch_bounds__(128) void gating_kernel(
    const float* __restrict__ x, const float* __restrict__ gw,
    const float* __restrict__ nw, const float* __restrict__ noise,
    int* counts, float* sums, int* tok_list, float* gate_list,
    int* tok_top, float* gate_top)
{
  __shared__ float s_gw[NEXP*DDIM];
  __shared__ float s_sums[NEXP];
  __shared__ float s_nw[NEXP];
  int tid = threadIdx.x;
  for (int i = tid; i < NEXP*DDIM/4; i += 128)
    ((f32x4*)s_gw)[i] = ((const f32x4*)gw)[i];
  if (tid < NEXP) { s_sums[tid] = 0.f; s_nw[tid] = nw[tid]; }
  __syncthreads();
  int t = blockIdx.x*128 + tid;
  float acc[NEXP];
  #pragma unroll
  for (int e = 0; e < NEXP; ++e) acc[e] = 0.f;
  const f32x4* xr = (const f32x4*)(x + (size_t)t*DDIM);
  for (int d4 = 0; d4 < DDIM/4; ++d4) {
    f32x4 xv = xr[d4];
    #pragma unroll
    for (int e = 0; e < NEXP; ++e) {
      f32x4 g = *(const f32x4*)&s_gw[e*DDIM + d4*4];
      acc[e] += xv.x*g.x + xv.y*g.y + xv.z*g.z + xv.w*g.w;
    }
  }
  float m = acc[0];
  #pragma unroll
  for (int e = 1; e < NEXP; ++e) m = fmaxf(m, acc[e]);
  float p[NEXP], s = 0.f;
  #pragma unroll
  for (int e = 0; e < NEXP; ++e) { p[e] = __expf(acc[e]-m); s += p[e]; }
  float inv = 1.f/s;
  #pragma unroll
  for (int e = 0; e < NEXP; ++e) atomicAdd(&s_sums[e], p[e]*inv);
  float ln[NEXP];
  #pragma unroll
  for (int e = 0; e < NEXP; ++e) ln[e] = acc[e] + noise[(size_t)t*NEXP+e]*s_nw[e];
  int i0 = 0; float v0 = ln[0];
  #pragma unroll
  for (int e = 1; e < NEXP; ++e) if (ln[e] > v0) { v0 = ln[e]; i0 = e; }
  int i1 = -1; float v1 = 0.f;
  #pragma unroll
  for (int e = 0; e < NEXP; ++e)
    if (e != i0 && (i1 < 0 || ln[e] > v1)) { v1 = ln[e]; i1 = e; }
  float e1 = __expf(v1 - v0);
  float g0 = 1.f/(1.f + e1);
  float g1 = e1*g0;
  int p0 = atomicAdd(&counts[i0], 1);
  tok_list[i0*NTOK + p0] = t; gate_list[i0*NTOK + p0] = g0;
  int p1 = atomicAdd(&counts[i1], 1);
  tok_list[i1*NTOK + p1] = t; gate_list[i1*NTOK + p1] = g1;
  tok_top[2*t] = i0; tok_top[2*t+1] = i1;
  gate_top[2*t] = g0; gate_top[2*t+1] = g1;
  __syncthreads();
  if (tid < NEXP) atomicAdd(&sums[tid], s_sums[tid]);
}

// ---------------- offsets prefix + load-balance loss ----------------
__global__ void finalize_kernel(const int* counts, const float* sums,
                                int* offsets, float* loss_out)
{
  if (threadIdx.x == 0) {
    int o = 0;
    #pragma unroll
    for (int e = 0; e < NEXP; ++e) { offsets[e] = o; o += counts[e]; }
    offsets[NEXP] = o;
    float l = 0.f;
    #pragma unroll
    for (int e = 0; e < NEXP; ++e) {
      float dv = sums[e]*(1.f/(float)NTOK) - 1.f/(float)NEXP;
      l += dv*dv;
    }
    loss_out[0] = l*(0.01f/(float)NEXP);
  }
}

// ---------------- x -> bf16 ----------------
__global__ __launch_bounds__(256) void cvt_x_kernel(const float* __restrict__ x,
                                                    unsigned short* __restrict__ xb)
{
  int i = blockIdx.x*256 + threadIdx.x;
  f32x4 v = ((const f32x4*)x)[i];
  u16x4 o; o.x = f2bf(v.x); o.y = f2bf(v.y); o.z = f2bf(v.z); o.w = f2bf(v.w);
  ((u16x4*)xb)[i] = o;
}

// ---------------- transpose+convert: src [E][R][C] f32 -> dst [E][C][R] bf16 ----
__global__ __launch_bounds__(256) void transpose_cvt_kernel(
    const float* __restrict__ src, unsigned short* __restrict__ dst, int R, int C)
{
  __shared__ unsigned short s[64*65];
  int e = blockIdx.z;
  int r0 = blockIdx.y*64, c0 = blockIdx.x*64;
  const float* sp = src + ((size_t)e*R + r0)*C + c0;
  unsigned short* dp = dst + ((size_t)e*C + c0)*R + r0;
  int t = threadIdx.x;
  #pragma unroll
  for (int i = 0; i < 16; ++i) {
    int idx = t + 256*i;
    int r = idx >> 6, c = idx & 63;
    s[c*65 + r] = f2bf(sp[(size_t)r*C + c]);
  }
  __syncthreads();
  #pragma unroll
  for (int i = 0; i < 16; ++i) {
    int idx = t + 256*i;
    int c = idx >> 6, r = idx & 63;
    dp[(size_t)c*R + r] = s[c*65 + r];
  }
}

// ---------------- compact per-expert lists into M=16384 rows ----------------
__global__ __launch_bounds__(256) void compact_kernel(
    const int* __restrict__ counts, const int* __restrict__ offsets,
    const int* __restrict__ tok_list, const float* __restrict__ gate_list,
    int* __restrict__ row_token, float* __restrict__ row_gate)
{
  int e = blockIdx.y;
  int pos = blockIdx.x*256 + threadIdx.x;
  if (pos < counts[e]) {
    int r = offsets[e] + pos;
    row_token[r] = tok_list[e*NTOK + pos];
    row_gate[r]  = gate_list[e*NTOK + pos];
  }
}

// ---------------- y init with gated biases (covers all outputs) ----------------
__global__ __launch_bounds__(256) void init_y_kernel(
    const int* __restrict__ tok_top, const float* __restrict__ gate_top,
    const float* __restrict__ bp, float* __restrict__ y)
{
  int i = blockIdx.x*256 + threadIdx.x;
  int t = i / (DDIM/4);
  int d4 = i % (DDIM/4);
  int e0 = tok_top[2*t], e1 = tok_top[2*t+1];
  float g0 = gate_top[2*t], g1 = gate_top[2*t+1];
  f32x4 b0 = ((const f32x4*)(bp + (size_t)e0*DDIM))[d4];
  f32x4 b1v = ((const f32x4*)(bp + (size_t)e1*DDIM))[d4];
  ((f32x4*)y)[i] = g0*b0 + g1*b1v;
}

// ---------------- FFN1 (MFMA, async staging): h = (x@w1+b1)*silu(x@w2+b2) ------
// 128 rows x 64 h-cols, both matrices. LDS: A 8KB | B1 4KB | B2 4KB.
// A gathered per-lane from xb via global_load_lds; B from bf16 [H][D] transposed.
__global__ __launch_bounds__(256) void ffn1_mfma(
    const unsigned short* __restrict__ xb,
    const unsigned short* __restrict__ w1T, const unsigned short* __restrict__ w2T,
    const float* __restrict__ b1, const float* __restrict__ b2,
    const int* __restrict__ offsets, const int* __restrict__ row_token,
    unsigned short* __restrict__ h_buf, int h_base, int HC)
{
  int e = blockIdx.z;
  int r_lo = offsets[e];
  int rows_e = offsets[e+1] - r_lo;
  int bx = blockIdx.x;
  if (bx*128 >= rows_e) return;
  int r0 = r_lo + bx*128;
  int rows_valid = rows_e - bx*128; if (rows_valid > 128) rows_valid = 128;
  int h0 = h_base + blockIdx.y*64;

  __shared__ __align__(16) char sL[16384];
  __shared__ int s_tok[128];

  int tid = threadIdx.x;
  if (tid < 128) {
    int r = r0 + tid; if (r > MROWS-1) r = MROWS-1;
    s_tok[tid] = row_token[r];
  }
  __syncthreads();
  int lane = tid & 63, wc = tid >> 6;
  int l4r = lane >> 2, l4c = lane & 3;
  int quad = lane >> 4, l16 = lane & 15;

  const unsigned short* gA0 = xb + (size_t)s_tok[wc*16 + l4r]*DDIM + l4c*8;
  const unsigned short* gA1 = xb + (size_t)s_tok[(wc+4)*16 + l4r]*DDIM + l4c*8;
  const unsigned short* gB1 = w1T + ((size_t)e*HDIM + h0 + wc*16 + l4r)*DDIM + l4c*8;
  const unsigned short* gB2 = w2T + ((size_t)e*HDIM + h0 + wc*16 + l4r)*DDIM + l4c*8;
  char* lA0 = sL + wc*1024;
  char* lA1 = sL + (wc+4)*1024;
  char* lB1 = sL + 8192 + wc*1024;
  char* lB2 = sL + 12288 + wc*1024;

  f32x4 acc1[8], acc2[8];
  #pragma unroll
  for (int i = 0; i < 8; ++i) { acc1[i] = (f32x4){0,0,0,0}; acc2[i] = (f32x4){0,0,0,0}; }

  for (int k0 = 0; k0 < DDIM; k0 += 32) {
    async16(gA0 + k0, lA0);
    async16(gA1 + k0, lA1);
    async16(gB1 + k0, lB1);
    async16(gB2 + k0, lB2);
    __syncthreads();
    bf16x8 bf1 = *(const bf16x8*)(sL + 8192 + (wc*16 + l16)*64 + quad*16);
    bf16x8 bf2 = *(const bf16x8*)(sL + 12288 + (wc*16 + l16)*64 + quad*16);
    #pragma unroll
    for (int mt = 0; mt < 8; ++mt) {
      bf16x8 af = *(const bf16x8*)(sL + (mt*16 + l16)*64 + quad*16);
      acc1[mt] = __builtin_amdgcn_mfma_f32_16x16x32_bf16(af, bf1, acc1[mt], 0, 0, 0);
      acc2[mt] = __builtin_amdgcn_mfma_f32_16x16x32_bf16(af, bf2, acc2[mt], 0, 0, 0);
    }
    __syncthreads();
  }
  // SwiGLU epilogue; C/D layout: col=lane&15, row=quad*4+reg
  int hcol = h0 + wc*16 + l16;
  float bb1 = b1[(size_t)e*HDIM + hcol];
  float bb2 = b2[(size_t)e*HDIM + hcol];
  int hl = hcol - h_base;
  #pragma unroll
  for (int mt = 0; mt < 8; ++mt) {
    #pragma unroll
    for (int r = 0; r < 4; ++r) {
      int row = mt*16 + quad*4 + r;
      if (row < rows_valid) {
        float c1 = acc1[mt][r] + bb1;
        float c2 = acc2[mt][r] + bb2;
        float hv = c1 * (c2 / (1.f + __expf(-c2)));
        h_buf[(size_t)(r0 + row)*HC + hl] = f2bf(hv);
      }
    }
  }
}

// ---------------- FFN2 (MFMA, async staging): y += gate*(h @ wp) ---------------
// 128 rows x 128 d-cols. LDS: A 8KB | B 8KB. B from bf16 wpT [D][H].
__global__ __launch_bounds__(256) void ffn2_mfma(
    const unsigned short* __restrict__ h_buf, const unsigned short* __restrict__ wpT,
    const int* __restrict__ offsets, const int* __restrict__ row_token,
    const float* __restrict__ row_gate, float* __restrict__ y, int h_base, int HC)
{
  int e = blockIdx.z;
  int r_lo = offsets[e];
  int rows_e = offsets[e+1] - r_lo;
  int bx = blockIdx.x;
  if (bx*128 >= rows_e) return;
  int r0 = r_lo + bx*128;
  int rows_valid = rows_e - bx*128; if (rows_valid > 128) rows_valid = 128;
  int c0 = blockIdx.y*128;

  __shared__ __align__(16) char sL[16384];
  __shared__ int s_tok[128];
  __shared__ float s_gate[128];

  int tid = threadIdx.x;
  if (tid < 128) {
    int r = r0 + tid; if (r > MROWS-1) r = MROWS-1;
    s_tok[tid]  = row_token[r];
    s_gate[tid] = row_gate[r];
  }
  int lane = tid & 63, wc = tid >> 6;
  int l4r = lane >> 2, l4c = lane & 3;
  int quad = lane >> 4, l16 = lane & 15;

  int rA0 = r0 + wc*16 + l4r;     if (rA0 > MROWS-1) rA0 = MROWS-1;
  int rA1 = r0 + (wc+4)*16 + l4r; if (rA1 > MROWS-1) rA1 = MROWS-1;
  const unsigned short* gA0 = h_buf + (size_t)rA0*HC + l4c*8;
  const unsigned short* gA1 = h_buf + (size_t)rA1*HC + l4c*8;
  const unsigned short* gB0 = wpT + ((size_t)e*DDIM + c0 + wc*16 + l4r)*HDIM + h_base + l4c*8;
  const unsigned short* gB1 = wpT + ((size_t)e*DDIM + c0 + (wc+4)*16 + l4r)*HDIM + h_base + l4c*8;
  char* lA0 = sL + wc*1024;
  char* lA1 = sL + (wc+4)*1024;
  char* lB0 = sL + 8192 + wc*1024;
  char* lB1 = sL + 8192 + (wc+4)*1024;

  f32x4 acc[8][2];
  #pragma unroll
  for (int i = 0; i < 8; ++i) { acc[i][0] = (f32x4){0,0,0,0}; acc[i][1] = (f32x4){0,0,0,0}; }
  __syncthreads();

  for (int k0 = 0; k0 < HC; k0 += 32) {
    async16(gA0 + k0, lA0);
    async16(gA1 + k0, lA1);
    async16(gB0 + k0, lB0);
    async16(gB1 + k0, lB1);
    __syncthreads();
    bf16x8 bfr0 = *(const bf16x8*)(sL + 8192 + (wc*32 + l16)*64 + quad*16);
    bf16x8 bfr1 = *(const bf16x8*)(sL + 8192 + (wc*32 + 16 + l16)*64 + quad*16);
    #pragma unroll
    for (int mt = 0; mt < 8; ++mt) {
      bf16x8 af = *(const bf16x8*)(sL + (mt*16 + l16)*64 + quad*16);
      acc[mt][0] = __builtin_amdgcn_mfma_f32_16x16x32_bf16(af, bfr0, acc[mt][0], 0, 0, 0);
      acc[mt][1] = __builtin_amdgcn_mfma_f32_16x16x32_bf16(af, bfr1, acc[mt][1], 0, 0, 0);
    }
    __syncthreads();
  }
  #pragma unroll
  for (int nt = 0; nt < 2; ++nt) {
    int col = c0 + wc*32 + nt*16 + l16;
    #pragma unroll
    for (int mt = 0; mt < 8; ++mt) {
      #pragma unroll
      for (int r = 0; r < 4; ++r) {
        int row = mt*16 + quad*4 + r;
        if (row < rows_valid)
          atomicAdd(&y[(size_t)s_tok[row]*DDIM + col], s_gate[row]*acc[mt][nt][r]);
      }
    }
  }
}

// ---------------- legacy FFN2 (fp32 B direct) — fallback when wpT doesn't fit --
__global__ __launch_bounds__(256) void ffn2_kernel(
    const unsigned short* __restrict__ h_buf, const float* __restrict__ wp,
    const int* __restrict__ offsets, const int* __restrict__ row_token,
    const float* __restrict__ row_gate, float* __restrict__ y, int h_base, int HC)
{
  int e = blockIdx.z;
  int r_lo = offsets[e];
  int rows_e = offsets[e+1] - r_lo;
  int bx = blockIdx.x;
  if (bx*128 >= rows_e) return;
  int r0 = r_lo + bx*128;
  int rows_valid = rows_e - bx*128; if (rows_valid > 128) rows_valid = 128;
  int c0 = blockIdx.y*128;

  __shared__ unsigned short sA[128*40];
  __shared__ int s_tok[128];
  __shared__ float s_gate[128];

  int tid = threadIdx.x;
  if (tid < 128) {
    int r = r0 + tid; if (r > MROWS-1) r = MROWS-1;
    s_tok[tid]  = row_token[r];
    s_gate[tid] = row_gate[r];
  }
  int lane = tid & 63;
  int wc = tid >> 6;
  int quad = lane >> 4, l16 = lane & 15;

  const float* wp0 = wp + (size_t)e*HDIM*DDIM + c0 + wc*32 + l16;

  f32x4 acc[8][2];
  #pragma unroll
  for (int i = 0; i < 8; ++i) { acc[i][0] = (f32x4){0,0,0,0}; acc[i][1] = (f32x4){0,0,0,0}; }
  __syncthreads();

  for (int k0 = 0; k0 < HC; k0 += 32) {
    #pragma unroll
    for (int i = 0; i < 2; ++i) {
      int c = i*256 + tid;
      int row = c >> 2, k8 = c & 3;
      int rr = r0 + row; if (rr > MROWS-1) rr = MROWS-1;
      bf16x8 v = *(const bf16x8*)(h_buf + (size_t)rr*HC + k0 + k8*8);
      *(bf16x8*)&sA[row*40 + k8*8] = v;
    }
    float bv[2][8];
    #pragma unroll
    for (int nt = 0; nt < 2; ++nt)
      #pragma unroll
      for (int j = 0; j < 8; ++j)
        bv[nt][j] = wp0[(size_t)(h_base + k0 + quad*8 + j)*DDIM + nt*16];
    bf16x8 bfr[2];
    #pragma unroll
    for (int nt = 0; nt < 2; ++nt)
      #pragma unroll
      for (int j = 0; j < 8; ++j) bfr[nt][j] = (short)f2bf(bv[nt][j]);
    __syncthreads();
    #pragma unroll
    for (int mt = 0; mt < 8; ++mt) {
      bf16x8 af = *(const bf16x8*)&sA[(mt*16 + l16)*40 + quad*8];
      acc[mt][0] = __builtin_amdgcn_mfma_f32_16x16x32_bf16(af, bfr[0], acc[mt][0], 0, 0, 0);
      acc[mt][1] = __builtin_amdgcn_mfma_f32_16x16x32_bf16(af, bfr[1], acc[mt][1], 0, 0, 0);
    }
    __syncthreads();
  }
  #pragma unroll
  for (int nt = 0; nt < 2; ++nt) {
    int col = c0 + wc*32 + nt*16 + l16;
    #pragma unroll
    for (int mt = 0; mt < 8; ++mt) {
      #pragma unroll
      for (int r = 0; r < 4; ++r) {
        int row = mt*16 + quad*4 + r;
        if (row < rows_valid)
          atomicAdd(&y[(size_t)s_tok[row]*DDIM + col], s_gate[row]*acc[mt][nt][r]);
      }
    }
  }
}

extern "C" void kernel_launch(void* const* d_in, const int* in_sizes, int n_in,
                              void* d_out, int out_size, void* d_ws, size_t ws_size,
                              hipStream_t stream)
{
  (void)in_sizes; (void)n_in; (void)out_size;
  const float* x     = (const float*)d_in[0];
  const float* gw    = (const float*)d_in[1];
  const float* nw    = (const float*)d_in[2];
  const float* noise = (const float*)d_in[3];
  const float* w1    = (const float*)d_in[4];
  const float* b1    = (const float*)d_in[5];
  const float* w2    = (const float*)d_in[6];
  const float* b2    = (const float*)d_in[7];
  const float* wp    = (const float*)d_in[8];
  const float* bp    = (const float*)d_in[9];
  float* y = (float*)d_out;

  char* ws = (char*)d_ws;
  int*   counts   = (int*)(ws + 0);
  float* sums     = (float*)(ws + 64);
  int*   offsets  = (int*)(ws + 128);
  size_t off = 256;
  int*   tok_list  = (int*)(ws + off);   off += (size_t)NEXP*NTOK*4;
  float* gate_list = (float*)(ws + off); off += (size_t)NEXP*NTOK*4;
  int*   tok_top   = (int*)(ws + off);   off += (size_t)NTOK*2*4;
  float* gate_top  = (float*)(ws + off); off += (size_t)NTOK*2*4;
  int*   row_token = (int*)(ws + off);   off += (size_t)MROWS*4;
  float* row_gate  = (float*)(ws + off); off += (size_t)MROWS*4;
  unsigned short* xb = (unsigned short*)(ws + off); off += (size_t)NTOK*DDIM*2;

  const size_t WT = (size_t)NEXP*DDIM*HDIM*2;   // one transposed bf16 weight set
  unsigned short* w1T = (unsigned short*)(ws + off);
  unsigned short* w2T = (unsigned short*)(ws + off + WT);
  unsigned short* wpT = (unsigned short*)(ws + off + 2*WT);
  bool haveP = (off + 3*WT + (size_t)MROWS*64*2 <= ws_size);
  size_t oH = off + (haveP ? 3*WT : 2*WT);

  static const int hc_opts[6] = {3072, 1536, 768, 384, 192, 64};
  int HC = 64;
  for (int i = 0; i < 6; ++i)
    if (oH + (size_t)MROWS*hc_opts[i]*2 <= ws_size) { HC = hc_opts[i]; break; }
  unsigned short* h_buf = (unsigned short*)(ws + oH);

  hipMemsetAsync(d_ws, 0, 256, stream);
  gating_kernel<<<NTOK/128, 128, 0, stream>>>(x, gw, nw, noise, counts, sums,
                                              tok_list, gate_list, tok_top, gate_top);
  finalize_kernel<<<1, 64, 0, stream>>>(counts, sums, offsets, y + (size_t)NTOK*DDIM);
  cvt_x_kernel<<<NTOK*DDIM/1024, 256, 0, stream>>>(x, xb);
  compact_kernel<<<dim3(NTOK/256, NEXP), 256, 0, stream>>>(counts, offsets, tok_list,
                                                           gate_list, row_token, row_gate);
  init_y_kernel<<<NTOK*DDIM/1024, 256, 0, stream>>>(tok_top, gate_top, bp, y);

  // weight transposes: w1/w2 [E][D][H] -> [E][H][D] bf16 ; wp [E][H][D] -> [E][D][H] bf16
  transpose_cvt_kernel<<<dim3(HDIM/64, DDIM/64, NEXP), 256, 0, stream>>>(w1, w1T, DDIM, HDIM);
  transpose_cvt_kernel<<<dim3(HDIM/64, DDIM/64, NEXP), 256, 0, stream>>>(w2, w2T, DDIM, HDIM);
  if (haveP)
    transpose_cvt_kernel<<<dim3(DDIM/64, HDIM/64, NEXP), 256, 0, stream>>>(wp, wpT, HDIM, DDIM);

  int nch = HDIM / HC;
  for (int c = 0; c < nch; ++c) {
    ffn1_mfma<<<dim3(64, HC/64, NEXP), 256, 0, stream>>>(xb, w1T, w2T, b1, b2, offsets,
                                                         row_token, h_buf, c*HC, HC);
    if (haveP)
      ffn2_mfma<<<dim3(64, DDIM/128, NEXP), 256, 0, stream>>>(h_buf, wpT, offsets, row_token,
                                                              row_gate, y, c*HC, HC);
    else
      ffn2_kernel<<<dim3(64, DDIM/128, NEXP), 256, 0, stream>>>(h_buf, wp, offsets, row_token,
                                                                row_gate, y, c*HC, HC);
  }
}